// Round 2
// baseline (449.144 us; speedup 1.0000x reference)
//
#include <hip/hip_runtime.h>
#include <cstdint>
#include <cstddef>

typedef __attribute__((ext_vector_type(4))) float  floatx4;
typedef __attribute__((ext_vector_type(8))) __bf16 bf16x8;
typedef __attribute__((ext_vector_type(4))) __bf16 bf16x4;

#define B_   2
#define T_   2048
#define D_   2048
#define H_   16
#define DK   128
#define BT_  (B_ * T_)    // 4096 rows
#define N3   (3 * D_)     // 6144

// async global->LDS, 16B per lane. LDS dest must be (wave-uniform base + lane*16).
__device__ __forceinline__ void async_copy16(const void* g, void* l) {
    __builtin_amdgcn_global_load_lds((const __attribute__((address_space(1))) void*)g,
                                     (__attribute__((address_space(3))) void*)l,
                                     16, 0, 0);
}

// ---------------------------------------------------------------------------
// prep kernels
// ---------------------------------------------------------------------------
__global__ void cast_bf16_kernel(const float* __restrict__ in, __bf16* __restrict__ out, int n4) {
    int i = blockIdx.x * 256 + threadIdx.x;
    if (i >= n4) return;
    float4 v = ((const float4*)in)[i];
    bf16x4 o;
    o.x = (__bf16)v.x; o.y = (__bf16)v.y; o.z = (__bf16)v.z; o.w = (__bf16)v.w;
    ((bf16x4*)out)[i] = o;
}

__global__ void transcast_kernel(const float* __restrict__ in, __bf16* __restrict__ out, int R, int C) {
    __shared__ float tile[32][33];
    int c0 = blockIdx.x * 32, r0 = blockIdx.y * 32;
    int tx = threadIdx.x, ty = threadIdx.y;
#pragma unroll
    for (int j = 0; j < 32; j += 8)
        tile[ty + j][tx] = in[(size_t)(r0 + ty + j) * C + c0 + tx];
    __syncthreads();
#pragma unroll
    for (int j = 0; j < 32; j += 8)
        out[(size_t)(c0 + ty + j) * R + r0 + tx] = (__bf16)tile[tx][ty + j];
}

__global__ void vtrans_kernel(const __bf16* __restrict__ kqv, __bf16* __restrict__ VT) {
    __shared__ __bf16 tile[32][33];
    int bh = blockIdx.z; int b = bh >> 4, h = bh & 15;
    int t0 = blockIdx.x * 32, d0 = blockIdx.y * 32;
    int tx = threadIdx.x, ty = threadIdx.y;
#pragma unroll
    for (int j = 0; j < 32; j += 8)
        tile[ty + j][tx] = kqv[(size_t)(b * T_ + t0 + ty + j) * N3 + 2 * D_ + h * DK + d0 + tx];
    __syncthreads();
#pragma unroll
    for (int j = 0; j < 32; j += 8)
        VT[(size_t)(bh * DK + d0 + ty + j) * T_ + t0 + tx] = tile[tx][ty + j];
}

// interleaved RoPE on k and q. Angle reduced to one revolution BEFORE trig so
// the fast small-arg path is always taken (on-device-trig trap, m205); then
// __sinf/__cosf (v_sin/v_cos based). q pre-scaled by log2(e)/sqrt(dk).
__global__ void rope_kernel(const __bf16* __restrict__ kqv,
                            __bf16* __restrict__ Kh, __bf16* __restrict__ Qh) {
    int idx = blockIdx.x * 256 + threadIdx.x;   // 2^23 threads exactly
    int i     = idx & 63;              // pair index 0..63
    int t     = (idx >> 6) & (T_ - 1);
    int bh    = (idx >> 17) & 31;
    int which = idx >> 22;             // 0 = k, 1 = q
    int b = bh >> 4, h = bh & 15;
    const __bf16* src = kqv + (size_t)(b * T_ + t) * N3 + which * D_ + h * DK + 2 * i;
    float x1 = (float)src[0], x2 = (float)src[1];
    // inv_freq/(2pi) = 10000^(-i/64) / (2pi)
    float freq_rev = 0.15915494309189535f * exp2f((float)i * (-13.287712379549449f / 64.f));
    float rev = (float)t * freq_rev;
    rev -= floorf(rev);                       // [0,1)
    float ang = rev * 6.283185307179586f;     // [0,2pi): fast trig path, exact weights to bf16
    float sn = __sinf(ang), cn = __cosf(ang);
    float s = which ? 0.12751740f : 1.0f;     // log2(e)/sqrt(128) folded into q
    __bf16* dst = (which ? Qh : Kh) + (size_t)(bh * T_ + t) * DK + 2 * i;
    dst[0] = (__bf16)((x1 * cn - x2 * sn) * s);
    dst[1] = (__bf16)((x1 * sn + x2 * cn) * s);
}

// ---------------------------------------------------------------------------
// m97-style GEMM (kept for GEMM2, whose 2048-wide N gives only 128 blocks at
// 256^2 tiles -- per-block arithmetic is a wash, so keep the proven kernel).
// ---------------------------------------------------------------------------
template <typename OutT>
__global__ __launch_bounds__(256)
void gemm_bt(const __bf16* __restrict__ A, const __bf16* __restrict__ BTm,
             const float* __restrict__ bias, OutT* __restrict__ C,
             int M, int N, int K) {
    __shared__ __align__(16) __bf16 As[128 * 64];
    __shared__ __align__(16) __bf16 Bs[128 * 64];
    const int tid  = threadIdx.x;
    const int lane = tid & 63;
    const int wave = tid >> 6;
    const int quad = lane >> 4;
    const int l16  = lane & 15;
    const int m0 = blockIdx.y * 128;
    const int n0 = blockIdx.x * 128;
    const int wm = (wave & 1) * 64;
    const int wn = (wave >> 1) * 64;

    const floatx4 z4 = {0.f, 0.f, 0.f, 0.f};
    floatx4 acc[4][4];
#pragma unroll
    for (int i = 0; i < 4; ++i)
#pragma unroll
        for (int j = 0; j < 4; ++j) acc[i][j] = z4;

    int           sOff[4];
    const __bf16* gA[4];
    const __bf16* gB[4];
#pragma unroll
    for (int i = 0; i < 4; ++i) {
        int s = i * 256 + tid;
        int row = s >> 3, cs = s & 7;
        int gc = cs ^ (row & 7);
        sOff[i] = s * 8;
        gA[i] = A   + (size_t)(m0 + row) * K + gc * 8;
        gB[i] = BTm + (size_t)(n0 + row) * K + gc * 8;
    }

    for (int kt = 0; kt < K; kt += 64) {
        __syncthreads();
#pragma unroll
        for (int i = 0; i < 4; ++i) {
            async_copy16(gA[i] + kt, As + sOff[i]);
            async_copy16(gB[i] + kt, Bs + sOff[i]);
        }
        __syncthreads();
#pragma unroll
        for (int ks2 = 0; ks2 < 2; ++ks2) {
            bf16x8 af[4], bf[4];
#pragma unroll
            for (int t = 0; t < 4; ++t) {
                int rowA = wm + t * 16 + l16;
                int ca = (ks2 * 4 + quad) ^ (rowA & 7);
                af[t] = *(const bf16x8*)(As + rowA * 64 + ca * 8);
                int rowB = wn + t * 16 + l16;
                int cb = (ks2 * 4 + quad) ^ (rowB & 7);
                bf[t] = *(const bf16x8*)(Bs + rowB * 64 + cb * 8);
            }
#pragma unroll
            for (int mt = 0; mt < 4; ++mt)
#pragma unroll
                for (int nt = 0; nt < 4; ++nt)
                    acc[mt][nt] = __builtin_amdgcn_mfma_f32_16x16x32_bf16(af[mt], bf[nt], acc[mt][nt], 0, 0, 0);
        }
    }

#pragma unroll
    for (int nt = 0; nt < 4; ++nt) {
        int n = n0 + wn + nt * 16 + l16;
        float bv = bias[n];
#pragma unroll
        for (int mt = 0; mt < 4; ++mt)
#pragma unroll
            for (int r = 0; r < 4; ++r) {
                int m = m0 + wm + mt * 16 + quad * 4 + r;
                C[(size_t)m * N + n] = (OutT)(acc[mt][nt][r] + bv);
            }
    }
}

// ---------------------------------------------------------------------------
// 256x256 8-phase GEMM (m201 port, plain HIP): C[M][N] = A[M][K]*BT[N][K]^T+bias.
// 512 threads = 8 waves (2M x 4N), per-wave 128x64 out (acc[8][4] f32x4).
// BK=64, LDS = 2 buf x (A 32K + B 32K) = 128 KB, XOR chunk swizzle (T2).
// Schedule (T3/T4): 8 phases per 2 K-tiles. Per tile: phase p reads A M-frag
// pair p (B all read in phase 0 and held in regs), so B frees after p0 and A
// frees quarter-per-phase. Each phase stages one 16 KB unit into regions freed
// >=1 phase earlier; counted vmcnt(6) at phases 3 and 7 only (3 units = 6
// loads in flight, never drained to 0 mid-loop). setprio wraps each 16-MFMA
// cluster (T5). Stage order per iteration (tiles tau=2i even->buf0, tau+1->buf1):
//   p0: Aq23(tau+1,buf1)  p1: Blo(tau+2,buf0)  p2: Bhi(tau+2)  p3: Aq01(tau+2) [vm6]
//   p4: Aq23(tau+2)       p5: Blo(tau+3,buf1)  p6: Bhi(tau+3)  p7: Aq01(tau+3) [vm6]
// Readiness: tile tau+1 complete by p3's vmcnt(6) (outstanding = p1..p3 stages);
// tile tau+2 complete by p7's vmcnt(6). WAR: every stage targets a region whose
// last ds_read finished before the previous closing barrier.
// ---------------------------------------------------------------------------
template <typename OutT>
__global__ __launch_bounds__(512, 2)
void gemm256(const __bf16* __restrict__ A, const __bf16* __restrict__ BTm,
             const float* __restrict__ bias, OutT* __restrict__ C,
             int M, int N, int K) {
    __shared__ __align__(16) __bf16 AS[2][256 * 64];   // 64 KB
    __shared__ __align__(16) __bf16 BS[2][256 * 64];   // 64 KB
    const int tid  = threadIdx.x;
    const int lane = tid & 63;
    const int quad = lane >> 4;
    const int l16  = lane & 15;
    const int wv   = tid >> 6;          // 0..7
    const int wm   = wv >> 2;           // 0..1  (M half)
    const int wn   = wv & 3;            // 0..3  (N quarter)

    // XCD-aware bijective swizzle (T1); grids here always have nwg % 8 == 0.
    int lin = blockIdx.y * gridDim.x + blockIdx.x;
    int qq  = (gridDim.x * gridDim.y) >> 3;
    int swz = (lin & 7) * qq + (lin >> 3);
    const int m0 = (swz / gridDim.x) * 256;
    const int n0 = (swz % gridDim.x) * 256;

    const floatx4 z4 = {0.f, 0.f, 0.f, 0.f};
    floatx4 acc[8][4];
#pragma unroll
    for (int i = 0; i < 8; ++i)
#pragma unroll
        for (int j = 0; j < 4; ++j) acc[i][j] = z4;

    // ---- staging address precompute (2 loads of 16B per thread per unit) ----
    // B unit u (0=rows 0-127, 1=rows 128-255): slot s = l*512+tid, row=s>>3,
    //   lds linear s*16 (+u*16KB), global chunk gc = (s&7)^(row&7).
    // A unit u (0 = rows {0-63,128-191} read in p0/p1; 1 = +64): r=s>>3,
    //   row = r<64 ? r : r+64; lds = row*128+(s&7)*16 (+u*8KB).
    int       ldsB[2], ldsA[2];
    const __bf16* gBp[2];
    const __bf16* gAp[2];
#pragma unroll
    for (int l = 0; l < 2; ++l) {
        int s = l * 512 + tid;
        int r = s >> 3, cs = s & 7;
        int gc = cs ^ (r & 7);
        ldsB[l] = s * 16;
        gBp[l]  = BTm + (size_t)(n0 + r) * K + gc * 8;
        int rowA = (r < 64) ? r : (r + 64);
        ldsA[l] = rowA * 128 + cs * 16;
        gAp[l]  = A + (size_t)(m0 + rowA) * K + gc * 8;
    }

#define STAGE_B(bufb, u, tile)                                                   \
    {                                                                            \
        _Pragma("unroll") for (int l = 0; l < 2; ++l)                            \
            async_copy16(gBp[l] + (size_t)(u) * 128 * K + (size_t)(tile) * 64,   \
                         (char*)&BS[(bufb)][0] + (u) * 16384 + ldsB[l]);         \
    }
#define STAGE_A(bufb, u, tile)                                                   \
    {                                                                            \
        _Pragma("unroll") for (int l = 0; l < 2; ++l)                            \
            async_copy16(gAp[l] + (size_t)(u) * 64 * K + (size_t)(tile) * 64,    \
                         (char*)&AS[(bufb)][0] + (u) * 8192 + ldsA[l]);          \
    }

    bf16x8 bfr[8];   // all B frags for current tile (held p0..p3)
    bf16x8 afr[4];   // current M-frag pair

#define PHASE(BUFB, MP, LOADB, STAGE_STMT, WAIT_STMT)                              \
    {                                                                              \
        if (LOADB) {                                                               \
            _Pragma("unroll") for (int nf = 0; nf < 4; ++nf)                       \
            _Pragma("unroll") for (int ks = 0; ks < 2; ++ks) {                     \
                int row = wn * 64 + nf * 16 + l16;                                 \
                int c = (ks * 4 + quad) ^ (row & 7);                               \
                bfr[nf * 2 + ks] = *(const bf16x8*)(&BS[BUFB][0] + row * 64 + c * 8); \
            }                                                                      \
        }                                                                          \
        _Pragma("unroll") for (int mi = 0; mi < 2; ++mi)                           \
        _Pragma("unroll") for (int ks = 0; ks < 2; ++ks) {                         \
            int row = wm * 128 + ((MP) * 2 + mi) * 16 + l16;                       \
            int c = (ks * 4 + quad) ^ (row & 7);                                   \
            afr[mi * 2 + ks] = *(const bf16x8*)(&AS[BUFB][0] + row * 64 + c * 8);  \
        }                                                                          \
        STAGE_STMT;                                                                \
        WAIT_STMT;                                                                 \
        __builtin_amdgcn_s_barrier();                                              \
        asm volatile("s_waitcnt lgkmcnt(0)" ::: "memory");                         \
        __builtin_amdgcn_sched_barrier(0);                                         \
        __builtin_amdgcn_s_setprio(1);                                             \
        _Pragma("unroll") for (int mi = 0; mi < 2; ++mi)                           \
        _Pragma("unroll") for (int nf = 0; nf < 4; ++nf)                           \
        _Pragma("unroll") for (int ks = 0; ks < 2; ++ks)                           \
            acc[(MP) * 2 + mi][nf] = __builtin_amdgcn_mfma_f32_16x16x32_bf16(      \
                afr[mi * 2 + ks], bfr[nf * 2 + ks], acc[(MP) * 2 + mi][nf], 0, 0, 0); \
        __builtin_amdgcn_s_setprio(0);                                             \
        __builtin_amdgcn_s_barrier();                                              \
    }

#define VM6 asm volatile("s_waitcnt vmcnt(6)" ::: "memory")
#define VM0 asm volatile("s_waitcnt vmcnt(0)" ::: "memory")

    const int nt    = K >> 6;    // K-tiles (K=2048 -> 32, even)
    const int niter = nt >> 1;

    // prologue: tile0 complete (4 units) + tile1 first 3 units
    STAGE_B(0, 0, 0); STAGE_B(0, 1, 0); STAGE_A(0, 0, 0); STAGE_A(0, 1, 0);
    STAGE_B(1, 0, 1); STAGE_B(1, 1, 1); STAGE_A(1, 0, 1);
    VM6;                                  // tile 0 landed; tile 1's 3 units in flight
    __builtin_amdgcn_s_barrier();

    for (int it = 0; it < niter; ++it) {
        const int tau  = 2 * it;
        const bool lst = (it == niter - 1);
        // ---- tile tau in buf 0 ----
        PHASE(0, 0, true,  { STAGE_A(1, 1, tau + 1); }, {});
        PHASE(0, 1, false, { if (!lst) STAGE_B(0, 0, tau + 2); }, {});
        PHASE(0, 2, false, { if (!lst) STAGE_B(0, 1, tau + 2); }, {});
        PHASE(0, 3, false, { if (!lst) STAGE_A(0, 0, tau + 2); }, { if (lst) { VM0; } else { VM6; } });
        // ---- tile tau+1 in buf 1 ----
        PHASE(1, 0, true,  { if (!lst) STAGE_A(0, 1, tau + 2); }, {});
        PHASE(1, 1, false, { if (!lst) STAGE_B(1, 0, tau + 3); }, {});
        PHASE(1, 2, false, { if (!lst) STAGE_B(1, 1, tau + 3); }, {});
        PHASE(1, 3, false, { if (!lst) STAGE_A(1, 0, tau + 3); }, { if (!lst) { VM6; } });
    }

#undef PHASE
#undef STAGE_A
#undef STAGE_B
#undef VM6
#undef VM0

    // epilogue
#pragma unroll
    for (int nf = 0; nf < 4; ++nf) {
        int n = n0 + wn * 64 + nf * 16 + l16;
        float bv = bias[n];
#pragma unroll
        for (int mf = 0; mf < 8; ++mf)
#pragma unroll
            for (int r = 0; r < 4; ++r) {
                int m = m0 + wm * 128 + mf * 16 + quad * 4 + r;
                C[(size_t)m * N + n] = (OutT)(acc[mf][nf][r] + bv);
            }
    }
}

// ---------------------------------------------------------------------------
// flash attention (R1 version: K/V double-buffered LDS, counted vmcnt(8),
// setprio around MFMA clusters; passed harness at 424.8 us).
// ---------------------------------------------------------------------------
__global__ __launch_bounds__(256)
void fa_kernel(const __bf16* __restrict__ Qg, const __bf16* __restrict__ Kg,
               const __bf16* __restrict__ VTg, __bf16* __restrict__ Og) {
    __shared__ __align__(16) __bf16 Ks[2][64 * 128];
    __shared__ __align__(16) __bf16 Vs[2][128 * 64];
    __shared__ __align__(16) __bf16 Ps[4][16 * 64];
    const int tid  = threadIdx.x;
    const int lane = tid & 63, wave = tid >> 6;
    const int quad = lane >> 4, l16 = lane & 15;
    const int bh = blockIdx.y;
    const int j  = blockIdx.x;
    const int b = bh >> 4, h = bh & 15;

    const __bf16* Kb = Kg  + (size_t)bh * T_ * DK;
    const __bf16* Vb = VTg + (size_t)bh * DK * T_;
    __bf16* Psw = Ps[wave];

    const floatx4 z4 = {0.f, 0.f, 0.f, 0.f};

    int           sK[4], sV[4];
    const __bf16* gK[4];
    const __bf16* gV[4];
#pragma unroll
    for (int i = 0; i < 4; ++i) {
        int s = i * 256 + tid;
        { int row = s >> 4, cs = s & 15; int gc = cs ^ (row & 7);
          sK[i] = s * 8; gK[i] = Kb + (size_t)row * DK + gc * 8; }
        { int row = s >> 3, cs = s & 7;  int gc = cs ^ (row & 7);
          sV[i] = s * 8; gV[i] = Vb + (size_t)row * T_ + gc * 8; }
    }

    for (int half = 0; half < 2; ++half) {
        const int qt = half ? (31 - j) : j;
        const int q0 = qt * 64;

        __syncthreads();
        {
            const __bf16* Qb = Qg + (size_t)(bh * T_ + q0) * DK;
#pragma unroll
            for (int i = 0; i < 4; ++i) {
                int s = i * 256 + tid;
                int row = s >> 4, cs = s & 15;
                int gc = cs ^ (row & 7);
                async_copy16(Qb + row * DK + gc * 8, &Ks[0][0] + s * 8);
            }
        }
        __syncthreads();
        bf16x8 qf[4];
#pragma unroll
        for (int ks = 0; ks < 4; ++ks) {
            int row = wave * 16 + l16;
            int c = (ks * 4 + quad) ^ (row & 7);
            qf[ks] = *(const bf16x8*)(&Ks[0][0] + row * DK + c * 8);
        }
        __syncthreads();

#pragma unroll
        for (int i = 0; i < 4; ++i) async_copy16(gK[i], &Ks[0][0] + sK[i]);
#pragma unroll
        for (int i = 0; i < 4; ++i) async_copy16(gV[i], &Vs[0][0] + sV[i]);

        float m_i[4], l_i[4];
        floatx4 accO[8];
#pragma unroll
        for (int r = 0; r < 4; ++r) { m_i[r] = -1e30f; l_i[r] = 0.f; }
#pragma unroll
        for (int nt = 0; nt < 8; ++nt) accO[nt] = z4;

        for (int kt = 0; kt <= qt; ++kt) {
            const int cur = kt & 1;
            if (kt < qt) {
                const int nb = cur ^ 1;
                const size_t koff = (size_t)(kt + 1) * 64 * DK;
                const size_t voff = (size_t)(kt + 1) * 64;
#pragma unroll
                for (int i = 0; i < 4; ++i) async_copy16(gK[i] + koff, &Ks[nb][0] + sK[i]);
#pragma unroll
                for (int i = 0; i < 4; ++i) async_copy16(gV[i] + voff, &Vs[nb][0] + sV[i]);
                asm volatile("s_waitcnt vmcnt(8)" ::: "memory");
            } else {
                asm volatile("s_waitcnt vmcnt(0)" ::: "memory");
            }
            __builtin_amdgcn_s_barrier();

            const __bf16* Kcur = &Ks[cur][0];
            const __bf16* Vcur = &Vs[cur][0];

            floatx4 sc[4];
#pragma unroll
            for (int nt = 0; nt < 4; ++nt) sc[nt] = z4;
            __builtin_amdgcn_s_setprio(1);
#pragma unroll
            for (int ks = 0; ks < 4; ++ks)
#pragma unroll
                for (int nt = 0; nt < 4; ++nt) {
                    int row = nt * 16 + l16;
                    int c = (ks * 4 + quad) ^ (row & 7);
                    bf16x8 kf = *(const bf16x8*)(Kcur + row * DK + c * 8);
                    sc[nt] = __builtin_amdgcn_mfma_f32_16x16x32_bf16(qf[ks], kf, sc[nt], 0, 0, 0);
                }
            __builtin_amdgcn_s_setprio(0);

            float mnew[4] = {-1e30f, -1e30f, -1e30f, -1e30f};
            if (kt == qt) {
                const int qrow0 = q0 + wave * 16 + quad * 4;
#pragma unroll
                for (int nt = 0; nt < 4; ++nt) {
                    int kp = kt * 64 + nt * 16 + l16;
#pragma unroll
                    for (int r = 0; r < 4; ++r) {
                        float v = sc[nt][r];
                        v = (kp > qrow0 + r) ? -1e30f : v;
                        sc[nt][r] = v;
                        mnew[r] = fmaxf(mnew[r], v);
                    }
                }
            } else {
#pragma unroll
                for (int nt = 0; nt < 4; ++nt)
#pragma unroll
                    for (int r = 0; r < 4; ++r) mnew[r] = fmaxf(mnew[r], sc[nt][r]);
            }
#pragma unroll
            for (int r = 0; r < 4; ++r) {
                float v = mnew[r];
                v = fmaxf(v, __shfl_xor(v, 1));
                v = fmaxf(v, __shfl_xor(v, 2));
                v = fmaxf(v, __shfl_xor(v, 4));
                v = fmaxf(v, __shfl_xor(v, 8));
                mnew[r] = v;
            }
            float alpha[4];
#pragma unroll
            for (int r = 0; r < 4; ++r) {
                float mi = fmaxf(m_i[r], mnew[r]);
                alpha[r] = exp2f(m_i[r] - mi);
                m_i[r] = mi;
            }
            float rs[4] = {0.f, 0.f, 0.f, 0.f};
#pragma unroll
            for (int nt = 0; nt < 4; ++nt)
#pragma unroll
                for (int r = 0; r < 4; ++r) {
                    float p = exp2f(sc[nt][r] - m_i[r]);
                    sc[nt][r] = p;
                    rs[r] += p;
                }
#pragma unroll
            for (int r = 0; r < 4; ++r) {
                float v = rs[r];
                v += __shfl_xor(v, 1);
                v += __shfl_xor(v, 2);
                v += __shfl_xor(v, 4);
                v += __shfl_xor(v, 8);
                l_i[r] = l_i[r] * alpha[r] + v;
            }
#pragma unroll
            for (int nt = 0; nt < 8; ++nt)
#pragma unroll
                for (int r = 0; r < 4; ++r) accO[nt][r] *= alpha[r];

#pragma unroll
            for (int nt = 0; nt < 4; ++nt) {
                int col = nt * 16 + l16;
                int ch = col >> 3, off = col & 7;
#pragma unroll
                for (int r = 0; r < 4; ++r) {
                    int row = quad * 4 + r;
                    Psw[row * 64 + (ch ^ (row & 7)) * 8 + off] = (__bf16)sc[nt][r];
                }
            }
            __builtin_amdgcn_s_setprio(1);
#pragma unroll
            for (int ks2 = 0; ks2 < 2; ++ks2) {
                int ach = (ks2 * 4 + quad) ^ (l16 & 7);
                bf16x8 pf = *(const bf16x8*)(Psw + l16 * 64 + ach * 8);
#pragma unroll
                for (int nt = 0; nt < 8; ++nt) {
                    int vrow = nt * 16 + l16;
                    int vch = (ks2 * 4 + quad) ^ (vrow & 7);
                    bf16x8 vf = *(const bf16x8*)(Vcur + vrow * 64 + vch * 8);
                    accO[nt] = __builtin_amdgcn_mfma_f32_16x16x32_bf16(pf, vf, accO[nt], 0, 0, 0);
                }
            }
            __builtin_amdgcn_s_setprio(0);

            __builtin_amdgcn_s_barrier();
        }

#pragma unroll
        for (int nt = 0; nt < 8; ++nt)
#pragma unroll
            for (int r = 0; r < 4; ++r) {
                int trow = q0 + wave * 16 + quad * 4 + r;
                int col = h * DK + nt * 16 + l16;
                Og[(size_t)(b * T_ + trow) * D_ + col] = (__bf16)(accO[nt][r] / l_i[r]);
            }
    }
}

// ---------------------------------------------------------------------------
extern "C" void kernel_launch(void* const* d_in, const int* in_sizes, int n_in,
                              void* d_out, int out_size, void* d_ws, size_t ws_size,
                              hipStream_t stream) {
    const float* x    = (const float*)d_in[0];
    const float* Wkqv = (const float*)d_in[1];
    const float* bkqv = (const float*)d_in[2];
    const float* Wo   = (const float*)d_in[3];
    const float* bo   = (const float*)d_in[4];
    float* out = (float*)d_out;

    char* p = (char*)d_ws;
    __bf16* xb    = (__bf16*)p; p += (size_t)BT_ * D_ * 2;
    __bf16* WkqvT = (__bf16*)p; p += (size_t)D_ * N3 * 2;
    __bf16* WoT   = (__bf16*)p; p += (size_t)D_ * D_ * 2;
    __bf16* kqv   = (__bf16*)p; p += (size_t)BT_ * N3 * 2;
    __bf16* qh    = (__bf16*)p; p += (size_t)BT_ * D_ * 2;
    __bf16* kh    = (__bf16*)p; p += (size_t)BT_ * D_ * 2;
    __bf16* vT    = (__bf16*)p; p += (size_t)BT_ * D_ * 2;
    __bf16* ao    = (__bf16*)p; p += (size_t)BT_ * D_ * 2;

    cast_bf16_kernel<<<(BT_ * D_ / 4 + 255) / 256, 256, 0, stream>>>(x, xb, BT_ * D_ / 4);
    transcast_kernel<<<dim3(N3 / 32, D_ / 32), dim3(32, 8), 0, stream>>>(Wkqv, WkqvT, D_, N3);
    transcast_kernel<<<dim3(D_ / 32, D_ / 32), dim3(32, 8), 0, stream>>>(Wo, WoT, D_, D_);
    gemm256<__bf16><<<dim3(N3 / 256, BT_ / 256), 512, 0, stream>>>(xb, WkqvT, bkqv, kqv, BT_, N3, D_);
    rope_kernel<<<(2 * 32 * T_ * 64) / 256, 256, 0, stream>>>(kqv, kh, qh);
    vtrans_kernel<<<dim3(T_ / 32, DK / 32, B_ * H_), dim3(32, 8), 0, stream>>>(kqv, vT);
    fa_kernel<<<dim3(16, B_ * H_), 256, 0, stream>>>(qh, kh, vT, ao);
    gemm_bt<float><<<dim3(D_ / 128, BT_ / 128), 256, 0, stream>>>(ao, WoT, bo, out, BT_, D_, D_);
}

// Round 3
// 435.315 us; speedup vs baseline: 1.0318x; 1.0318x over previous
//
#include <hip/hip_runtime.h>
#include <cstdint>
#include <cstddef>

typedef __attribute__((ext_vector_type(4))) float  floatx4;
typedef __attribute__((ext_vector_type(8))) __bf16 bf16x8;
typedef __attribute__((ext_vector_type(4))) __bf16 bf16x4;

#define B_   2
#define T_   2048
#define D_   2048
#define H_   16
#define DK   128
#define BT_  (B_ * T_)    // 4096 rows
#define N3   (3 * D_)     // 6144

// async global->LDS, 16B per lane. LDS dest must be (wave-uniform base + lane*16).
__device__ __forceinline__ void async_copy16(const void* g, void* l) {
    __builtin_amdgcn_global_load_lds((const __attribute__((address_space(1))) void*)g,
                                     (__attribute__((address_space(3))) void*)l,
                                     16, 0, 0);
}

// ---------------------------------------------------------------------------
// prep kernels
// ---------------------------------------------------------------------------
__global__ void cast_bf16_kernel(const float* __restrict__ in, __bf16* __restrict__ out, int n4) {
    int i = blockIdx.x * 256 + threadIdx.x;
    if (i >= n4) return;
    float4 v = ((const float4*)in)[i];
    bf16x4 o;
    o.x = (__bf16)v.x; o.y = (__bf16)v.y; o.z = (__bf16)v.z; o.w = (__bf16)v.w;
    ((bf16x4*)out)[i] = o;
}

__global__ void transcast_kernel(const float* __restrict__ in, __bf16* __restrict__ out, int R, int C) {
    __shared__ float tile[32][33];
    int c0 = blockIdx.x * 32, r0 = blockIdx.y * 32;
    int tx = threadIdx.x, ty = threadIdx.y;
#pragma unroll
    for (int j = 0; j < 32; j += 8)
        tile[ty + j][tx] = in[(size_t)(r0 + ty + j) * C + c0 + tx];
    __syncthreads();
#pragma unroll
    for (int j = 0; j < 32; j += 8)
        out[(size_t)(c0 + ty + j) * R + r0 + tx] = (__bf16)tile[tx][ty + j];
}

// ---------------------------------------------------------------------------
// m97-style GEMM, BK=64 (proven 132us/781TF structure): C = A * BT^T + bias.
// 128x128 tile, 4 waves, global_load_lds width-16 staging, XOR chunk swizzle.
// ---------------------------------------------------------------------------
template <typename OutT>
__global__ __launch_bounds__(256)
void gemm_bt(const __bf16* __restrict__ A, const __bf16* __restrict__ BTm,
             const float* __restrict__ bias, OutT* __restrict__ C,
             int M, int N, int K) {
    __shared__ __align__(16) __bf16 As[128 * 64];
    __shared__ __align__(16) __bf16 Bs[128 * 64];
    const int tid  = threadIdx.x;
    const int lane = tid & 63;
    const int wave = tid >> 6;
    const int quad = lane >> 4;
    const int l16  = lane & 15;
    const int m0 = blockIdx.y * 128;
    const int n0 = blockIdx.x * 128;
    const int wm = (wave & 1) * 64;
    const int wn = (wave >> 1) * 64;

    const floatx4 z4 = {0.f, 0.f, 0.f, 0.f};
    floatx4 acc[4][4];
#pragma unroll
    for (int i = 0; i < 4; ++i)
#pragma unroll
        for (int j = 0; j < 4; ++j) acc[i][j] = z4;

    int           sOff[4];
    const __bf16* gA[4];
    const __bf16* gB[4];
#pragma unroll
    for (int i = 0; i < 4; ++i) {
        int s = i * 256 + tid;
        int row = s >> 3, cs = s & 7;
        int gc = cs ^ (row & 7);
        sOff[i] = s * 8;
        gA[i] = A   + (size_t)(m0 + row) * K + gc * 8;
        gB[i] = BTm + (size_t)(n0 + row) * K + gc * 8;
    }

    for (int kt = 0; kt < K; kt += 64) {
        __syncthreads();
#pragma unroll
        for (int i = 0; i < 4; ++i) {
            async_copy16(gA[i] + kt, As + sOff[i]);
            async_copy16(gB[i] + kt, Bs + sOff[i]);
        }
        __syncthreads();
#pragma unroll
        for (int ks2 = 0; ks2 < 2; ++ks2) {
            bf16x8 af[4], bf[4];
#pragma unroll
            for (int t = 0; t < 4; ++t) {
                int rowA = wm + t * 16 + l16;
                int ca = (ks2 * 4 + quad) ^ (rowA & 7);
                af[t] = *(const bf16x8*)(As + rowA * 64 + ca * 8);
                int rowB = wn + t * 16 + l16;
                int cb = (ks2 * 4 + quad) ^ (rowB & 7);
                bf[t] = *(const bf16x8*)(Bs + rowB * 64 + cb * 8);
            }
#pragma unroll
            for (int mt = 0; mt < 4; ++mt)
#pragma unroll
                for (int nt = 0; nt < 4; ++nt)
                    acc[mt][nt] = __builtin_amdgcn_mfma_f32_16x16x32_bf16(af[mt], bf[nt], acc[mt][nt], 0, 0, 0);
        }
    }

#pragma unroll
    for (int nt = 0; nt < 4; ++nt) {
        int n = n0 + wn + nt * 16 + l16;
        float bv = bias[n];
#pragma unroll
        for (int mt = 0; mt < 4; ++mt)
#pragma unroll
            for (int r = 0; r < 4; ++r) {
                int m = m0 + wm + mt * 16 + quad * 4 + r;
                C[(size_t)m * N + n] = (OutT)(acc[mt][nt][r] + bv);
            }
    }
}

// ---------------------------------------------------------------------------
// GEMM1 with FUSED rope + head-split + V-transpose epilogue.
// Main loop identical to gemm_bt. Epilogue: each element kqv[m][n] (fp32 in
// acc) is bias-added, then routed by which = n>>11:
//   which=0 (k): RoPE -> Kh[(b*16+h)*T + t][dd]
//   which=1 (q): RoPE * log2e/sqrt(128) -> Qh (base-2 softmax prescale)
//   which=2 (v): VT[((b*16+h)*128+dd)*T + t]   (transposed store)
// RoPE pairing: partner column n^1 lives in lane^1 at the same (mt,r)
// (n = n0+wn+nt*16+l16), so one __shfl_xor(val,1) provides the pair.
// `which` is wave-uniform (16-value n-span cannot straddle a 2048 boundary).
// Rope on fp32 pre-round values (more accurate than the old bf16 path).
// Wave covers full (t x dd) blocks -> L2 write-combines the 2B stores.
// ---------------------------------------------------------------------------
__global__ __launch_bounds__(256)
void gemm_kqv(const __bf16* __restrict__ A, const __bf16* __restrict__ BTm,
              const float* __restrict__ bias,
              __bf16* __restrict__ Kh, __bf16* __restrict__ Qh,
              __bf16* __restrict__ VT,
              int M, int N, int K) {
    __shared__ __align__(16) __bf16 As[128 * 64];
    __shared__ __align__(16) __bf16 Bs[128 * 64];
    const int tid  = threadIdx.x;
    const int lane = tid & 63;
    const int wave = tid >> 6;
    const int quad = lane >> 4;
    const int l16  = lane & 15;
    const int m0 = blockIdx.y * 128;
    const int n0 = blockIdx.x * 128;
    const int wm = (wave & 1) * 64;
    const int wn = (wave >> 1) * 64;

    const floatx4 z4 = {0.f, 0.f, 0.f, 0.f};
    floatx4 acc[4][4];
#pragma unroll
    for (int i = 0; i < 4; ++i)
#pragma unroll
        for (int j = 0; j < 4; ++j) acc[i][j] = z4;

    int           sOff[4];
    const __bf16* gA[4];
    const __bf16* gB[4];
#pragma unroll
    for (int i = 0; i < 4; ++i) {
        int s = i * 256 + tid;
        int row = s >> 3, cs = s & 7;
        int gc = cs ^ (row & 7);
        sOff[i] = s * 8;
        gA[i] = A   + (size_t)(m0 + row) * K + gc * 8;
        gB[i] = BTm + (size_t)(n0 + row) * K + gc * 8;
    }

    for (int kt = 0; kt < K; kt += 64) {
        __syncthreads();
#pragma unroll
        for (int i = 0; i < 4; ++i) {
            async_copy16(gA[i] + kt, As + sOff[i]);
            async_copy16(gB[i] + kt, Bs + sOff[i]);
        }
        __syncthreads();
#pragma unroll
        for (int ks2 = 0; ks2 < 2; ++ks2) {
            bf16x8 af[4], bf[4];
#pragma unroll
            for (int t = 0; t < 4; ++t) {
                int rowA = wm + t * 16 + l16;
                int ca = (ks2 * 4 + quad) ^ (rowA & 7);
                af[t] = *(const bf16x8*)(As + rowA * 64 + ca * 8);
                int rowB = wn + t * 16 + l16;
                int cb = (ks2 * 4 + quad) ^ (rowB & 7);
                bf[t] = *(const bf16x8*)(Bs + rowB * 64 + cb * 8);
            }
#pragma unroll
            for (int mt = 0; mt < 4; ++mt)
#pragma unroll
                for (int nt = 0; nt < 4; ++nt)
                    acc[mt][nt] = __builtin_amdgcn_mfma_f32_16x16x32_bf16(af[mt], bf[nt], acc[mt][nt], 0, 0, 0);
        }
    }

    // ---- fused epilogue ----
#pragma unroll
    for (int nt = 0; nt < 4; ++nt) {
        const int n   = n0 + wn + nt * 16 + l16;
        const float bv = bias[n];
        const int which = n >> 11;          // 0=k, 1=q, 2=v (D_=2048)
        const int nin   = n & (D_ - 1);
        const int h  = nin >> 7;
        const int dd = nin & 127;
        // rope frequency (revolutions per t): 10000^(-(dd>>1)/64) / (2pi)
        const float freq_rev = 0.15915494309189535f *
                               exp2f((float)(dd >> 1) * (-13.287712379549449f / 64.f));
        const float qscale = (which == 1) ? 0.12751740f : 1.0f;  // log2e/sqrt(128)
#pragma unroll
        for (int mt = 0; mt < 4; ++mt)
#pragma unroll
            for (int r = 0; r < 4; ++r) {
                const int m = m0 + wm + mt * 16 + quad * 4 + r;
                const int b = m >> 11;        // T_=2048
                const int t = m & (T_ - 1);
                const int bh = b * H_ + h;
                const float val = acc[mt][nt][r] + bv;
                if (which == 2) {
                    VT[((size_t)bh * DK + dd) * T_ + t] = (__bf16)val;
                } else {
                    const float other = __shfl_xor(val, 1);
                    const float x1 = (dd & 1) ? other : val;   // even-col value
                    const float x2 = (dd & 1) ? val : other;   // odd-col value
                    float rev = (float)t * freq_rev;
                    rev -= floorf(rev);
                    const float ang = rev * 6.283185307179586f;
                    const float sn = __sinf(ang), cn = __cosf(ang);
                    const float res = (dd & 1) ? (x1 * sn + x2 * cn)
                                               : (x1 * cn - x2 * sn);
                    __bf16* dst = (which == 1) ? Qh : Kh;
                    dst[((size_t)bh * T_ + t) * DK + dd] = (__bf16)(res * qscale);
                }
            }
    }
}

// ---------------------------------------------------------------------------
// flash attention (verified R1 version: K/V double-buffered LDS, counted
// vmcnt(8), setprio around MFMA clusters). Unchanged this round.
// ---------------------------------------------------------------------------
__global__ __launch_bounds__(256)
void fa_kernel(const __bf16* __restrict__ Qg, const __bf16* __restrict__ Kg,
               const __bf16* __restrict__ VTg, __bf16* __restrict__ Og) {
    __shared__ __align__(16) __bf16 Ks[2][64 * 128];
    __shared__ __align__(16) __bf16 Vs[2][128 * 64];
    __shared__ __align__(16) __bf16 Ps[4][16 * 64];
    const int tid  = threadIdx.x;
    const int lane = tid & 63, wave = tid >> 6;
    const int quad = lane >> 4, l16 = lane & 15;
    const int bh = blockIdx.y;
    const int j  = blockIdx.x;
    const int b = bh >> 4, h = bh & 15;

    const __bf16* Kb = Kg  + (size_t)bh * T_ * DK;
    const __bf16* Vb = VTg + (size_t)bh * DK * T_;
    __bf16* Psw = Ps[wave];

    const floatx4 z4 = {0.f, 0.f, 0.f, 0.f};

    int           sK[4], sV[4];
    const __bf16* gK[4];
    const __bf16* gV[4];
#pragma unroll
    for (int i = 0; i < 4; ++i) {
        int s = i * 256 + tid;
        { int row = s >> 4, cs = s & 15; int gc = cs ^ (row & 7);
          sK[i] = s * 8; gK[i] = Kb + (size_t)row * DK + gc * 8; }
        { int row = s >> 3, cs = s & 7;  int gc = cs ^ (row & 7);
          sV[i] = s * 8; gV[i] = Vb + (size_t)row * T_ + gc * 8; }
    }

    for (int half = 0; half < 2; ++half) {
        const int qt = half ? (31 - j) : j;
        const int q0 = qt * 64;

        __syncthreads();
        {
            const __bf16* Qb = Qg + (size_t)(bh * T_ + q0) * DK;
#pragma unroll
            for (int i = 0; i < 4; ++i) {
                int s = i * 256 + tid;
                int row = s >> 4, cs = s & 15;
                int gc = cs ^ (row & 7);
                async_copy16(Qb + row * DK + gc * 8, &Ks[0][0] + s * 8);
            }
        }
        __syncthreads();
        bf16x8 qf[4];
#pragma unroll
        for (int ks = 0; ks < 4; ++ks) {
            int row = wave * 16 + l16;
            int c = (ks * 4 + quad) ^ (row & 7);
            qf[ks] = *(const bf16x8*)(&Ks[0][0] + row * DK + c * 8);
        }
        __syncthreads();

#pragma unroll
        for (int i = 0; i < 4; ++i) async_copy16(gK[i], &Ks[0][0] + sK[i]);
#pragma unroll
        for (int i = 0; i < 4; ++i) async_copy16(gV[i], &Vs[0][0] + sV[i]);

        float m_i[4], l_i[4];
        floatx4 accO[8];
#pragma unroll
        for (int r = 0; r < 4; ++r) { m_i[r] = -1e30f; l_i[r] = 0.f; }
#pragma unroll
        for (int nt = 0; nt < 8; ++nt) accO[nt] = z4;

        for (int kt = 0; kt <= qt; ++kt) {
            const int cur = kt & 1;
            if (kt < qt) {
                const int nb = cur ^ 1;
                const size_t koff = (size_t)(kt + 1) * 64 * DK;
                const size_t voff = (size_t)(kt + 1) * 64;
#pragma unroll
                for (int i = 0; i < 4; ++i) async_copy16(gK[i] + koff, &Ks[nb][0] + sK[i]);
#pragma unroll
                for (int i = 0; i < 4; ++i) async_copy16(gV[i] + voff, &Vs[nb][0] + sV[i]);
                asm volatile("s_waitcnt vmcnt(8)" ::: "memory");
            } else {
                asm volatile("s_waitcnt vmcnt(0)" ::: "memory");
            }
            __builtin_amdgcn_s_barrier();

            const __bf16* Kcur = &Ks[cur][0];
            const __bf16* Vcur = &Vs[cur][0];

            floatx4 sc[4];
#pragma unroll
            for (int nt = 0; nt < 4; ++nt) sc[nt] = z4;
            __builtin_amdgcn_s_setprio(1);
#pragma unroll
            for (int ks = 0; ks < 4; ++ks)
#pragma unroll
                for (int nt = 0; nt < 4; ++nt) {
                    int row = nt * 16 + l16;
                    int c = (ks * 4 + quad) ^ (row & 7);
                    bf16x8 kf = *(const bf16x8*)(Kcur + row * DK + c * 8);
                    sc[nt] = __builtin_amdgcn_mfma_f32_16x16x32_bf16(qf[ks], kf, sc[nt], 0, 0, 0);
                }
            __builtin_amdgcn_s_setprio(0);

            float mnew[4] = {-1e30f, -1e30f, -1e30f, -1e30f};
            if (kt == qt) {
                const int qrow0 = q0 + wave * 16 + quad * 4;
#pragma unroll
                for (int nt = 0; nt < 4; ++nt) {
                    int kp = kt * 64 + nt * 16 + l16;
#pragma unroll
                    for (int r = 0; r < 4; ++r) {
                        float v = sc[nt][r];
                        v = (kp > qrow0 + r) ? -1e30f : v;
                        sc[nt][r] = v;
                        mnew[r] = fmaxf(mnew[r], v);
                    }
                }
            } else {
#pragma unroll
                for (int nt = 0; nt < 4; ++nt)
#pragma unroll
                    for (int r = 0; r < 4; ++r) mnew[r] = fmaxf(mnew[r], sc[nt][r]);
            }
#pragma unroll
            for (int r = 0; r < 4; ++r) {
                float v = mnew[r];
                v = fmaxf(v, __shfl_xor(v, 1));
                v = fmaxf(v, __shfl_xor(v, 2));
                v = fmaxf(v, __shfl_xor(v, 4));
                v = fmaxf(v, __shfl_xor(v, 8));
                mnew[r] = v;
            }
            float alpha[4];
#pragma unroll
            for (int r = 0; r < 4; ++r) {
                float mi = fmaxf(m_i[r], mnew[r]);
                alpha[r] = exp2f(m_i[r] - mi);
                m_i[r] = mi;
            }
            float rs[4] = {0.f, 0.f, 0.f, 0.f};
#pragma unroll
            for (int nt = 0; nt < 4; ++nt)
#pragma unroll
                for (int r = 0; r < 4; ++r) {
                    float p = exp2f(sc[nt][r] - m_i[r]);
                    sc[nt][r] = p;
                    rs[r] += p;
                }
#pragma unroll
            for (int r = 0; r < 4; ++r) {
                float v = rs[r];
                v += __shfl_xor(v, 1);
                v += __shfl_xor(v, 2);
                v += __shfl_xor(v, 4);
                v += __shfl_xor(v, 8);
                l_i[r] = l_i[r] * alpha[r] + v;
            }
#pragma unroll
            for (int nt = 0; nt < 8; ++nt)
#pragma unroll
                for (int r = 0; r < 4; ++r) accO[nt][r] *= alpha[r];

#pragma unroll
            for (int nt = 0; nt < 4; ++nt) {
                int col = nt * 16 + l16;
                int ch = col >> 3, off = col & 7;
#pragma unroll
                for (int r = 0; r < 4; ++r) {
                    int row = quad * 4 + r;
                    Psw[row * 64 + (ch ^ (row & 7)) * 8 + off] = (__bf16)sc[nt][r];
                }
            }
            __builtin_amdgcn_s_setprio(1);
#pragma unroll
            for (int ks2 = 0; ks2 < 2; ++ks2) {
                int ach = (ks2 * 4 + quad) ^ (l16 & 7);
                bf16x8 pf = *(const bf16x8*)(Psw + l16 * 64 + ach * 8);
#pragma unroll
                for (int nt = 0; nt < 8; ++nt) {
                    int vrow = nt * 16 + l16;
                    int vch = (ks2 * 4 + quad) ^ (vrow & 7);
                    bf16x8 vf = *(const bf16x8*)(Vcur + vrow * 64 + vch * 8);
                    accO[nt] = __builtin_amdgcn_mfma_f32_16x16x32_bf16(pf, vf, accO[nt], 0, 0, 0);
                }
            }
            __builtin_amdgcn_s_setprio(0);

            __builtin_amdgcn_s_barrier();
        }

#pragma unroll
        for (int nt = 0; nt < 8; ++nt)
#pragma unroll
            for (int r = 0; r < 4; ++r) {
                int trow = q0 + wave * 16 + quad * 4 + r;
                int col = h * DK + nt * 16 + l16;
                Og[(size_t)(b * T_ + trow) * D_ + col] = (__bf16)(accO[nt][r] / l_i[r]);
            }
    }
}

// ---------------------------------------------------------------------------
extern "C" void kernel_launch(void* const* d_in, const int* in_sizes, int n_in,
                              void* d_out, int out_size, void* d_ws, size_t ws_size,
                              hipStream_t stream) {
    const float* x    = (const float*)d_in[0];
    const float* Wkqv = (const float*)d_in[1];
    const float* bkqv = (const float*)d_in[2];
    const float* Wo   = (const float*)d_in[3];
    const float* bo   = (const float*)d_in[4];
    float* out = (float*)d_out;

    char* p = (char*)d_ws;
    __bf16* xb    = (__bf16*)p; p += (size_t)BT_ * D_ * 2;  // 16 MiB
    __bf16* WkqvT = (__bf16*)p; p += (size_t)D_ * N3 * 2;   // 24 MiB
    __bf16* WoT   = (__bf16*)p; p += (size_t)D_ * D_ * 2;   //  8 MiB
    __bf16* qh    = (__bf16*)p; p += (size_t)BT_ * D_ * 2;  // 16 MiB
    __bf16* kh    = (__bf16*)p; p += (size_t)BT_ * D_ * 2;  // 16 MiB
    __bf16* vT    = (__bf16*)p; p += (size_t)BT_ * D_ * 2;  // 16 MiB
    __bf16* ao    = (__bf16*)p; p += (size_t)BT_ * D_ * 2;  // 16 MiB

    cast_bf16_kernel<<<(BT_ * D_ / 4 + 255) / 256, 256, 0, stream>>>(x, xb, BT_ * D_ / 4);
    transcast_kernel<<<dim3(N3 / 32, D_ / 32), dim3(32, 8), 0, stream>>>(Wkqv, WkqvT, D_, N3);
    transcast_kernel<<<dim3(D_ / 32, D_ / 32), dim3(32, 8), 0, stream>>>(Wo, WoT, D_, D_);
    gemm_kqv<<<dim3(N3 / 128, BT_ / 128), 256, 0, stream>>>(xb, WkqvT, bkqv, kh, qh, vT, BT_, N3, D_);
    fa_kernel<<<dim3(16, B_ * H_), 256, 0, stream>>>(qh, kh, vT, ao);
    gemm_bt<float><<<dim3(D_ / 128, BT_ / 128), 256, 0, stream>>>(ao, WoT, bo, out, BT_, D_, D_);
}

// Round 4
// 406.995 us; speedup vs baseline: 1.1036x; 1.0696x over previous
//
#include <hip/hip_runtime.h>
#include <cstdint>
#include <cstddef>

typedef __attribute__((ext_vector_type(4))) float  floatx4;
typedef __attribute__((ext_vector_type(8))) __bf16 bf16x8;
typedef __attribute__((ext_vector_type(4))) __bf16 bf16x4;

#define B_   2
#define T_   2048
#define D_   2048
#define H_   16
#define DK   128
#define BT_  (B_ * T_)    // 4096 rows
#define N3   (3 * D_)     // 6144

// async global->LDS, 16B per lane. LDS dest must be (wave-uniform base + lane*16).
__device__ __forceinline__ void async_copy16(const void* g, void* l) {
    __builtin_amdgcn_global_load_lds((const __attribute__((address_space(1))) void*)g,
                                     (__attribute__((address_space(3))) void*)l,
                                     16, 0, 0);
}

// ---------------------------------------------------------------------------
// prep kernels
// ---------------------------------------------------------------------------
__global__ void cast_bf16_kernel(const float* __restrict__ in, __bf16* __restrict__ out, int n4) {
    int i = blockIdx.x * 256 + threadIdx.x;
    if (i >= n4) return;
    float4 v = ((const float4*)in)[i];
    bf16x4 o;
    o.x = (__bf16)v.x; o.y = (__bf16)v.y; o.z = (__bf16)v.z; o.w = (__bf16)v.w;
    ((bf16x4*)out)[i] = o;
}

__global__ void transcast_kernel(const float* __restrict__ in, __bf16* __restrict__ out, int R, int C) {
    __shared__ float tile[32][33];
    int c0 = blockIdx.x * 32, r0 = blockIdx.y * 32;
    int tx = threadIdx.x, ty = threadIdx.y;
#pragma unroll
    for (int j = 0; j < 32; j += 8)
        tile[ty + j][tx] = in[(size_t)(r0 + ty + j) * C + c0 + tx];
    __syncthreads();
#pragma unroll
    for (int j = 0; j < 32; j += 8)
        out[(size_t)(c0 + ty + j) * R + r0 + tx] = (__bf16)tile[tx][ty + j];
}

// kqv v-part [b*T+t][2D + h*128 + dd] -> VT [bh][dd][t]  (LDS-tiled: coalesced
// both sides; avoids the 2B-scatter write inflation the fused epilogue showed)
__global__ void vtrans_kernel(const __bf16* __restrict__ kqv, __bf16* __restrict__ VT) {
    __shared__ __bf16 tile[32][33];
    int bh = blockIdx.z; int b = bh >> 4, h = bh & 15;
    int t0 = blockIdx.x * 32, d0 = blockIdx.y * 32;
    int tx = threadIdx.x, ty = threadIdx.y;
#pragma unroll
    for (int j = 0; j < 32; j += 8)
        tile[ty + j][tx] = kqv[(size_t)(b * T_ + t0 + ty + j) * N3 + 2 * D_ + h * DK + d0 + tx];
    __syncthreads();
#pragma unroll
    for (int j = 0; j < 32; j += 8)
        VT[(size_t)(bh * DK + d0 + ty + j) * T_ + t0 + tx] = tile[tx][ty + j];
}

// interleaved RoPE on k and q (R2 verified version: revolution-reduced fast
// trig). q pre-scaled by log2(e)/sqrt(dk) -> fa softmax runs in base-2.
__global__ void rope_kernel(const __bf16* __restrict__ kqv,
                            __bf16* __restrict__ Kh, __bf16* __restrict__ Qh) {
    int idx = blockIdx.x * 256 + threadIdx.x;   // 2^23 threads exactly
    int i     = idx & 63;              // pair index 0..63
    int t     = (idx >> 6) & (T_ - 1);
    int bh    = (idx >> 17) & 31;
    int which = idx >> 22;             // 0 = k, 1 = q
    int b = bh >> 4, h = bh & 15;
    const __bf16* src = kqv + (size_t)(b * T_ + t) * N3 + which * D_ + h * DK + 2 * i;
    float x1 = (float)src[0], x2 = (float)src[1];
    float freq_rev = 0.15915494309189535f * exp2f((float)i * (-13.287712379549449f / 64.f));
    float rev = (float)t * freq_rev;
    rev -= floorf(rev);
    float ang = rev * 6.283185307179586f;
    float sn = __sinf(ang), cn = __cosf(ang);
    float s = which ? 0.12751740f : 1.0f;   // log2(e)/sqrt(128) folded into q
    __bf16* dst = (which ? Qh : Kh) + (size_t)(bh * T_ + t) * DK + 2 * i;
    dst[0] = (__bf16)((x1 * cn - x2 * sn) * s);
    dst[1] = (__bf16)((x1 * sn + x2 * cn) * s);
}

// ---------------------------------------------------------------------------
// m97-style GEMM, BK=64 (proven 132us/781TF structure): C = A * BT^T + bias.
// ---------------------------------------------------------------------------
template <typename OutT>
__global__ __launch_bounds__(256)
void gemm_bt(const __bf16* __restrict__ A, const __bf16* __restrict__ BTm,
             const float* __restrict__ bias, OutT* __restrict__ C,
             int M, int N, int K) {
    __shared__ __align__(16) __bf16 As[128 * 64];
    __shared__ __align__(16) __bf16 Bs[128 * 64];
    const int tid  = threadIdx.x;
    const int lane = tid & 63;
    const int wave = tid >> 6;
    const int quad = lane >> 4;
    const int l16  = lane & 15;
    const int m0 = blockIdx.y * 128;
    const int n0 = blockIdx.x * 128;
    const int wm = (wave & 1) * 64;
    const int wn = (wave >> 1) * 64;

    const floatx4 z4 = {0.f, 0.f, 0.f, 0.f};
    floatx4 acc[4][4];
#pragma unroll
    for (int i = 0; i < 4; ++i)
#pragma unroll
        for (int j = 0; j < 4; ++j) acc[i][j] = z4;

    int           sOff[4];
    const __bf16* gA[4];
    const __bf16* gB[4];
#pragma unroll
    for (int i = 0; i < 4; ++i) {
        int s = i * 256 + tid;
        int row = s >> 3, cs = s & 7;
        int gc = cs ^ (row & 7);
        sOff[i] = s * 8;
        gA[i] = A   + (size_t)(m0 + row) * K + gc * 8;
        gB[i] = BTm + (size_t)(n0 + row) * K + gc * 8;
    }

    for (int kt = 0; kt < K; kt += 64) {
        __syncthreads();
#pragma unroll
        for (int i = 0; i < 4; ++i) {
            async_copy16(gA[i] + kt, As + sOff[i]);
            async_copy16(gB[i] + kt, Bs + sOff[i]);
        }
        __syncthreads();
#pragma unroll
        for (int ks2 = 0; ks2 < 2; ++ks2) {
            bf16x8 af[4], bf[4];
#pragma unroll
            for (int t = 0; t < 4; ++t) {
                int rowA = wm + t * 16 + l16;
                int ca = (ks2 * 4 + quad) ^ (rowA & 7);
                af[t] = *(const bf16x8*)(As + rowA * 64 + ca * 8);
                int rowB = wn + t * 16 + l16;
                int cb = (ks2 * 4 + quad) ^ (rowB & 7);
                bf[t] = *(const bf16x8*)(Bs + rowB * 64 + cb * 8);
            }
#pragma unroll
            for (int mt = 0; mt < 4; ++mt)
#pragma unroll
                for (int nt = 0; nt < 4; ++nt)
                    acc[mt][nt] = __builtin_amdgcn_mfma_f32_16x16x32_bf16(af[mt], bf[nt], acc[mt][nt], 0, 0, 0);
        }
    }

#pragma unroll
    for (int nt = 0; nt < 4; ++nt) {
        int n = n0 + wn + nt * 16 + l16;
        float bv = bias[n];
#pragma unroll
        for (int mt = 0; mt < 4; ++mt)
#pragma unroll
            for (int r = 0; r < 4; ++r) {
                int m = m0 + wm + mt * 16 + quad * 4 + r;
                C[(size_t)m * N + n] = (OutT)(acc[mt][nt][r] + bv);
            }
    }
}

// ---------------------------------------------------------------------------
// flash attention, SWAPPED-OPERAND redesign.
// QK^T computed as mfma(kf, qf) -> S^T: col=l16=q-row, row=quad*4+r=k.
// Each lane owns ONE q-row (wave*16+l16): softmax state m,l,alpha are lane
// scalars; row-reduce = 15 in-lane fmax + 2 shfl_xor(16,32) (vs 32 shfls).
// P written to per-wave LDS as 4x ds_write_b64 (8B-group XOR swizzle, <=2-way
// bank conflict), read back as 2x b128 B-frags. PV computed as
// O^T = mfma(vf, pb): vf is the IDENTICAL Vs A-frag read; accO holds O^T
// (col=q, row=d-within-16). K/V double-buffered LDS + counted vmcnt(8) +
// setprio retained from the verified R1 schedule.
//   Fragment-load identities (vs old kernel): kf, qf, vf reads unchanged;
//   only mfma argument order and P/softmax/epilogue indexing changed.
// ---------------------------------------------------------------------------
__global__ __launch_bounds__(256)
void fa_kernel(const __bf16* __restrict__ Qg, const __bf16* __restrict__ Kg,
               const __bf16* __restrict__ VTg, __bf16* __restrict__ Og) {
    __shared__ __align__(16) __bf16 Ks[2][64 * 128];   // 32KB
    __shared__ __align__(16) __bf16 Vs[2][128 * 64];   // 32KB
    __shared__ __align__(16) __bf16 Ps[4][16 * 64];    //  8KB (per-wave 2KB)
    const int tid  = threadIdx.x;
    const int lane = tid & 63, wave = tid >> 6;
    const int quad = lane >> 4, l16 = lane & 15;
    const int bh = blockIdx.y;
    const int j  = blockIdx.x;          // 0..15
    const int b = bh >> 4, h = bh & 15;

    const __bf16* Kb = Kg  + (size_t)bh * T_ * DK;
    const __bf16* Vb = VTg + (size_t)bh * DK * T_;
    __bf16* Psw = Ps[wave];
    const int swzP = (l16 & 7) << 1;    // even XOR mask on 4-elem (8B) groups

    const floatx4 z4 = {0.f, 0.f, 0.f, 0.f};

    int           sK[4], sV[4];
    const __bf16* gK[4];
    const __bf16* gV[4];
#pragma unroll
    for (int i = 0; i < 4; ++i) {
        int s = i * 256 + tid;
        { int row = s >> 4, cs = s & 15; int gc = cs ^ (row & 7);
          sK[i] = s * 8; gK[i] = Kb + (size_t)row * DK + gc * 8; }
        { int row = s >> 3, cs = s & 7;  int gc = cs ^ (row & 7);
          sV[i] = s * 8; gV[i] = Vb + (size_t)row * T_ + gc * 8; }
    }

    for (int half = 0; half < 2; ++half) {
        const int qt = half ? (31 - j) : j;
        const int q0 = qt * 64;
        const int qpos = q0 + wave * 16 + l16;   // this lane's q-row

        // ---- prologue: stage Q tile through Ks[0], lift to registers ----
        __syncthreads();   // WAR: previous half's reads of Ks/Vs (full drain)
        {
            const __bf16* Qb = Qg + (size_t)(bh * T_ + q0) * DK;
#pragma unroll
            for (int i = 0; i < 4; ++i) {
                int s = i * 256 + tid;
                int row = s >> 4, cs = s & 15;
                int gc = cs ^ (row & 7);
                async_copy16(Qb + row * DK + gc * 8, &Ks[0][0] + s * 8);
            }
        }
        __syncthreads();   // vmcnt(0): Q staged
        bf16x8 qf[4];
#pragma unroll
        for (int ks = 0; ks < 4; ++ks) {
            int row = wave * 16 + l16;
            int c = (ks * 4 + quad) ^ (row & 7);
            qf[ks] = *(const bf16x8*)(&Ks[0][0] + row * DK + c * 8);
        }
        __syncthreads();   // lgkmcnt(0): qf in registers before Ks[0] overwrite

        // prologue prefetch: tile 0 -> buf 0
#pragma unroll
        for (int i = 0; i < 4; ++i) async_copy16(gK[i], &Ks[0][0] + sK[i]);
#pragma unroll
        for (int i = 0; i < 4; ++i) async_copy16(gV[i], &Vs[0][0] + sV[i]);

        float m_i = -1e30f, l_i = 0.f;
        floatx4 accO[8];   // O^T tiles: accO[dt] -> d = dt*16+quad*4+r, q = l16
#pragma unroll
        for (int dt = 0; dt < 8; ++dt) accO[dt] = z4;

        for (int kt = 0; kt <= qt; ++kt) {
            const int cur = kt & 1;
            if (kt < qt) {
                const int nb = cur ^ 1;
                const size_t koff = (size_t)(kt + 1) * 64 * DK;
                const size_t voff = (size_t)(kt + 1) * 64;
#pragma unroll
                for (int i = 0; i < 4; ++i) async_copy16(gK[i] + koff, &Ks[nb][0] + sK[i]);
#pragma unroll
                for (int i = 0; i < 4; ++i) async_copy16(gV[i] + voff, &Vs[nb][0] + sV[i]);
                asm volatile("s_waitcnt vmcnt(8)" ::: "memory");
            } else {
                asm volatile("s_waitcnt vmcnt(0)" ::: "memory");
            }
            __builtin_amdgcn_s_barrier();

            const __bf16* Kcur = &Ks[cur][0];
            const __bf16* Vcur = &Vs[cur][0];

            // S^T strip: sc[nt] covers k = kt*64+nt*16+quad*4+r, q = l16
            floatx4 sc[4];
#pragma unroll
            for (int nt = 0; nt < 4; ++nt) sc[nt] = z4;
            __builtin_amdgcn_s_setprio(1);
#pragma unroll
            for (int ks = 0; ks < 4; ++ks)
#pragma unroll
                for (int nt = 0; nt < 4; ++nt) {
                    int row = nt * 16 + l16;
                    int c = (ks * 4 + quad) ^ (row & 7);
                    bf16x8 kf = *(const bf16x8*)(Kcur + row * DK + c * 8);
                    sc[nt] = __builtin_amdgcn_mfma_f32_16x16x32_bf16(kf, qf[ks], sc[nt], 0, 0, 0);
                }
            __builtin_amdgcn_s_setprio(0);

            // causal mask + in-lane max over own 16 k-values
            float mnew = -1e30f;
            if (kt == qt) {
#pragma unroll
                for (int nt = 0; nt < 4; ++nt) {
                    int kbase = kt * 64 + nt * 16 + quad * 4;
#pragma unroll
                    for (int r = 0; r < 4; ++r) {
                        float v = sc[nt][r];
                        v = (kbase + r > qpos) ? -1e30f : v;
                        sc[nt][r] = v;
                        mnew = fmaxf(mnew, v);
                    }
                }
            } else {
#pragma unroll
                for (int nt = 0; nt < 4; ++nt)
#pragma unroll
                    for (int r = 0; r < 4; ++r) mnew = fmaxf(mnew, sc[nt][r]);
            }
            // cross-quad reduce (q-row spread over lanes l16, l16+16, +32, +48)
            mnew = fmaxf(mnew, __shfl_xor(mnew, 16));
            mnew = fmaxf(mnew, __shfl_xor(mnew, 32));
            const float mi = fmaxf(m_i, mnew);
            const float alpha = exp2f(m_i - mi);   // base-2 softmax
            m_i = mi;

            float rs = 0.f;
#pragma unroll
            for (int nt = 0; nt < 4; ++nt)
#pragma unroll
                for (int r = 0; r < 4; ++r) {
                    float pv = exp2f(sc[nt][r] - mi);
                    sc[nt][r] = pv;
                    rs += pv;
                }
            rs += __shfl_xor(rs, 16);
            rs += __shfl_xor(rs, 32);
            l_i = l_i * alpha + rs;
#pragma unroll
            for (int dt = 0; dt < 8; ++dt)
#pragma unroll
                for (int r = 0; r < 4; ++r) accO[dt][r] *= alpha;

            // P^T -> LDS: row q=l16 (64 k's), 8B groups swizzled by g^=swzP
#pragma unroll
            for (int nt = 0; nt < 4; ++nt) {
                bf16x4 pw;
                pw.x = (__bf16)sc[nt][0]; pw.y = (__bf16)sc[nt][1];
                pw.z = (__bf16)sc[nt][2]; pw.w = (__bf16)sc[nt][3];
                int g = (nt * 4 + quad) ^ swzP;
                *(bf16x4*)(Psw + l16 * 64 + g * 4) = pw;
            }
            // O^T += V^T . P^T  (A = Vs rows, B = P^T frags from Psw)
            __builtin_amdgcn_s_setprio(1);
#pragma unroll
            for (int kc = 0; kc < 2; ++kc) {
                int gk = (kc * 8 + quad * 2) ^ swzP;   // even -> 16B aligned
                bf16x8 pb = *(const bf16x8*)(Psw + l16 * 64 + gk * 4);
#pragma unroll
                for (int dt = 0; dt < 8; ++dt) {
                    int vrow = dt * 16 + l16;
                    int vch = (kc * 4 + quad) ^ (vrow & 7);
                    bf16x8 vf = *(const bf16x8*)(Vcur + vrow * 64 + vch * 8);
                    accO[dt] = __builtin_amdgcn_mfma_f32_16x16x32_bf16(vf, pb, accO[dt], 0, 0, 0);
                }
            }
            __builtin_amdgcn_s_setprio(0);

            __builtin_amdgcn_s_barrier();
        }

        // ---- epilogue: accO is O^T; lane writes 8x 8B runs of its q-row ----
        const float inv = 1.0f / l_i;
        __bf16* orow = Og + (size_t)(b * T_ + qpos) * D_ + h * DK;
#pragma unroll
        for (int dt = 0; dt < 8; ++dt) {
            bf16x4 ow;
            ow.x = (__bf16)(accO[dt][0] * inv);
            ow.y = (__bf16)(accO[dt][1] * inv);
            ow.z = (__bf16)(accO[dt][2] * inv);
            ow.w = (__bf16)(accO[dt][3] * inv);
            *(bf16x4*)(orow + dt * 16 + quad * 4) = ow;
        }
    }
}

// ---------------------------------------------------------------------------
extern "C" void kernel_launch(void* const* d_in, const int* in_sizes, int n_in,
                              void* d_out, int out_size, void* d_ws, size_t ws_size,
                              hipStream_t stream) {
    const float* x    = (const float*)d_in[0];
    const float* Wkqv = (const float*)d_in[1];
    const float* bkqv = (const float*)d_in[2];
    const float* Wo   = (const float*)d_in[3];
    const float* bo   = (const float*)d_in[4];
    float* out = (float*)d_out;

    // workspace layout (160 MiB total)
    char* p = (char*)d_ws;
    __bf16* xb    = (__bf16*)p; p += (size_t)BT_ * D_ * 2;  // 16 MiB
    __bf16* WkqvT = (__bf16*)p; p += (size_t)D_ * N3 * 2;   // 24 MiB
    __bf16* WoT   = (__bf16*)p; p += (size_t)D_ * D_ * 2;   //  8 MiB
    __bf16* kqv   = (__bf16*)p; p += (size_t)BT_ * N3 * 2;  // 48 MiB
    __bf16* qh    = (__bf16*)p; p += (size_t)BT_ * D_ * 2;  // 16 MiB
    __bf16* kh    = (__bf16*)p; p += (size_t)BT_ * D_ * 2;  // 16 MiB
    __bf16* vT    = (__bf16*)p; p += (size_t)BT_ * D_ * 2;  // 16 MiB
    __bf16* ao    = (__bf16*)p; p += (size_t)BT_ * D_ * 2;  // 16 MiB

    cast_bf16_kernel<<<(BT_ * D_ / 4 + 255) / 256, 256, 0, stream>>>(x, xb, BT_ * D_ / 4);
    transcast_kernel<<<dim3(N3 / 32, D_ / 32), dim3(32, 8), 0, stream>>>(Wkqv, WkqvT, D_, N3);
    transcast_kernel<<<dim3(D_ / 32, D_ / 32), dim3(32, 8), 0, stream>>>(Wo, WoT, D_, D_);
    gemm_bt<__bf16><<<dim3(N3 / 128, BT_ / 128), 256, 0, stream>>>(xb, WkqvT, bkqv, kqv, BT_, N3, D_);
    rope_kernel<<<(2 * 32 * T_ * 64) / 256, 256, 0, stream>>>(kqv, kh, qh);
    vtrans_kernel<<<dim3(T_ / 32, DK / 32, B_ * H_), dim3(32, 8), 0, stream>>>(kqv, vT);
    fa_kernel<<<dim3(16, B_ * H_), 256, 0, stream>>>(qh, kh, vT, ao);
    gemm_bt<float><<<dim3(D_ / 128, BT_ / 128), 256, 0, stream>>>(ao, WoT, bo, out, BT_, D_, D_);
}

// Round 5
// 397.311 us; speedup vs baseline: 1.1305x; 1.0244x over previous
//
#include <hip/hip_runtime.h>
#include <cstdint>
#include <cstddef>

typedef __attribute__((ext_vector_type(4))) float  floatx4;
typedef __attribute__((ext_vector_type(8))) __bf16 bf16x8;
typedef __attribute__((ext_vector_type(4))) __bf16 bf16x4;

#define B_   2
#define T_   2048
#define D_   2048
#define H_   16
#define DK   128
#define BT_  (B_ * T_)    // 4096 rows
#define N3   (3 * D_)     // 6144

// async global->LDS, 16B per lane. LDS dest must be (wave-uniform base + lane*16).
__device__ __forceinline__ void async_copy16(const void* g, void* l) {
    __builtin_amdgcn_global_load_lds((const __attribute__((address_space(1))) void*)g,
                                     (__attribute__((address_space(3))) void*)l,
                                     16, 0, 0);
}

// ---------------------------------------------------------------------------
// prep kernels
// ---------------------------------------------------------------------------
__global__ void cast_bf16_kernel(const float* __restrict__ in, __bf16* __restrict__ out, int n4) {
    int i = blockIdx.x * 256 + threadIdx.x;
    if (i >= n4) return;
    float4 v = ((const float4*)in)[i];
    bf16x4 o;
    o.x = (__bf16)v.x; o.y = (__bf16)v.y; o.z = (__bf16)v.z; o.w = (__bf16)v.w;
    ((bf16x4*)out)[i] = o;
}

__global__ void transcast_kernel(const float* __restrict__ in, __bf16* __restrict__ out, int R, int C) {
    __shared__ float tile[32][33];
    int c0 = blockIdx.x * 32, r0 = blockIdx.y * 32;
    int tx = threadIdx.x, ty = threadIdx.y;
#pragma unroll
    for (int j = 0; j < 32; j += 8)
        tile[ty + j][tx] = in[(size_t)(r0 + ty + j) * C + c0 + tx];
    __syncthreads();
#pragma unroll
    for (int j = 0; j < 32; j += 8)
        out[(size_t)(c0 + ty + j) * R + r0 + tx] = (__bf16)tile[tx][ty + j];
}

// ---------------------------------------------------------------------------
// m97-style GEMM, BK=64 (proven 132us/781TF structure): C = A * BT^T + bias.
// Used for GEMM2 (out-projection).
// ---------------------------------------------------------------------------
template <typename OutT>
__global__ __launch_bounds__(256)
void gemm_bt(const __bf16* __restrict__ A, const __bf16* __restrict__ BTm,
             const float* __restrict__ bias, OutT* __restrict__ C,
             int M, int N, int K) {
    __shared__ __align__(16) __bf16 As[128 * 64];
    __shared__ __align__(16) __bf16 Bs[128 * 64];
    const int tid  = threadIdx.x;
    const int lane = tid & 63;
    const int wave = tid >> 6;
    const int quad = lane >> 4;
    const int l16  = lane & 15;
    const int m0 = blockIdx.y * 128;
    const int n0 = blockIdx.x * 128;
    const int wm = (wave & 1) * 64;
    const int wn = (wave >> 1) * 64;

    const floatx4 z4 = {0.f, 0.f, 0.f, 0.f};
    floatx4 acc[4][4];
#pragma unroll
    for (int i = 0; i < 4; ++i)
#pragma unroll
        for (int j = 0; j < 4; ++j) acc[i][j] = z4;

    int           sOff[4];
    const __bf16* gA[4];
    const __bf16* gB[4];
#pragma unroll
    for (int i = 0; i < 4; ++i) {
        int s = i * 256 + tid;
        int row = s >> 3, cs = s & 7;
        int gc = cs ^ (row & 7);
        sOff[i] = s * 8;
        gA[i] = A   + (size_t)(m0 + row) * K + gc * 8;
        gB[i] = BTm + (size_t)(n0 + row) * K + gc * 8;
    }

    for (int kt = 0; kt < K; kt += 64) {
        __syncthreads();
#pragma unroll
        for (int i = 0; i < 4; ++i) {
            async_copy16(gA[i] + kt, As + sOff[i]);
            async_copy16(gB[i] + kt, Bs + sOff[i]);
        }
        __syncthreads();
#pragma unroll
        for (int ks2 = 0; ks2 < 2; ++ks2) {
            bf16x8 af[4], bf[4];
#pragma unroll
            for (int t = 0; t < 4; ++t) {
                int rowA = wm + t * 16 + l16;
                int ca = (ks2 * 4 + quad) ^ (rowA & 7);
                af[t] = *(const bf16x8*)(As + rowA * 64 + ca * 8);
                int rowB = wn + t * 16 + l16;
                int cb = (ks2 * 4 + quad) ^ (rowB & 7);
                bf[t] = *(const bf16x8*)(Bs + rowB * 64 + cb * 8);
            }
#pragma unroll
            for (int mt = 0; mt < 4; ++mt)
#pragma unroll
                for (int nt = 0; nt < 4; ++nt)
                    acc[mt][nt] = __builtin_amdgcn_mfma_f32_16x16x32_bf16(af[mt], bf[nt], acc[mt][nt], 0, 0, 0);
        }
    }

#pragma unroll
    for (int nt = 0; nt < 4; ++nt) {
        int n = n0 + wn + nt * 16 + l16;
        float bv = bias[n];
#pragma unroll
        for (int mt = 0; mt < 4; ++mt)
#pragma unroll
            for (int r = 0; r < 4; ++r) {
                int m = m0 + wm + mt * 16 + quad * 4 + r;
                C[(size_t)m * N + n] = (OutT)(acc[mt][nt][r] + bv);
            }
    }
}

// ---------------------------------------------------------------------------
// GEMM1 with FUSED rope + head-split + V-transpose epilogue (R3 retry; the V
// scatter that cost R3 +17us is replaced by an LDS transpose + 16B stores).
// Main loop identical to gemm_bt (As/Bs carved from a shared smem buffer that
// the V epilogue reuses as a 128x136-padded transpose tile).
//  which = n0>>11 (block-uniform): 0=k -> RoPE -> Kh[bh][t][dd]
//                                  1=q -> RoPE*log2e/sqrt(128) -> Qh
//                                  2=v -> LDS transpose -> VT[bh][dd][t]
// K/Q store pattern == gemm_bt's C-write (measured non-amplifying, R4:
// WRITE_SIZE 50.3MB = ideal). RoPE pairing: partner col n^1 lives in lane^1
// at the same (mt,r); one __shfl_xor(val,1). Rope on fp32 pre-round values.
// V path: smem[dd*136+t] (stride 136 -> 16B-aligned rows, <=2-way-conflict
// b128 reads), then 8 passes of 256 threads = 16B/lane fully-coalesced rows.
// ---------------------------------------------------------------------------
__global__ __launch_bounds__(256)
void gemm_kqv(const __bf16* __restrict__ A, const __bf16* __restrict__ BTm,
              const float* __restrict__ bias,
              __bf16* __restrict__ Kh, __bf16* __restrict__ Qh,
              __bf16* __restrict__ VT,
              int M, int N, int K) {
    __shared__ __align__(16) __bf16 smem[128 * 136];   // 34 KB: As|Bs, then V-transpose
    __bf16* As = smem;
    __bf16* Bs = smem + 128 * 64;
    const int tid  = threadIdx.x;
    const int lane = tid & 63;
    const int wave = tid >> 6;
    const int quad = lane >> 4;
    const int l16  = lane & 15;
    const int m0 = blockIdx.y * 128;
    const int n0 = blockIdx.x * 128;
    const int wm = (wave & 1) * 64;
    const int wn = (wave >> 1) * 64;

    const floatx4 z4 = {0.f, 0.f, 0.f, 0.f};
    floatx4 acc[4][4];
#pragma unroll
    for (int i = 0; i < 4; ++i)
#pragma unroll
        for (int j = 0; j < 4; ++j) acc[i][j] = z4;

    int           sOff[4];
    const __bf16* gA[4];
    const __bf16* gB[4];
#pragma unroll
    for (int i = 0; i < 4; ++i) {
        int s = i * 256 + tid;
        int row = s >> 3, cs = s & 7;
        int gc = cs ^ (row & 7);
        sOff[i] = s * 8;
        gA[i] = A   + (size_t)(m0 + row) * K + gc * 8;
        gB[i] = BTm + (size_t)(n0 + row) * K + gc * 8;
    }

    for (int kt = 0; kt < K; kt += 64) {
        __syncthreads();
#pragma unroll
        for (int i = 0; i < 4; ++i) {
            async_copy16(gA[i] + kt, As + sOff[i]);
            async_copy16(gB[i] + kt, Bs + sOff[i]);
        }
        __syncthreads();
#pragma unroll
        for (int ks2 = 0; ks2 < 2; ++ks2) {
            bf16x8 af[4], bf[4];
#pragma unroll
            for (int t = 0; t < 4; ++t) {
                int rowA = wm + t * 16 + l16;
                int ca = (ks2 * 4 + quad) ^ (rowA & 7);
                af[t] = *(const bf16x8*)(As + rowA * 64 + ca * 8);
                int rowB = wn + t * 16 + l16;
                int cb = (ks2 * 4 + quad) ^ (rowB & 7);
                bf[t] = *(const bf16x8*)(Bs + rowB * 64 + cb * 8);
            }
#pragma unroll
            for (int mt = 0; mt < 4; ++mt)
#pragma unroll
                for (int nt = 0; nt < 4; ++nt)
                    acc[mt][nt] = __builtin_amdgcn_mfma_f32_16x16x32_bf16(af[mt], bf[nt], acc[mt][nt], 0, 0, 0);
        }
    }

    // ---- fused epilogue ----
    const int which = n0 >> 11;               // 0=k,1=q,2=v (block-uniform)
    const int h  = (n0 & (D_ - 1)) >> 7;
    const int b  = m0 >> 11;
    const int t0 = m0 & (T_ - 1);
    const int bh = b * H_ + h;

    if (which == 2) {
        // V: transpose through LDS, then coalesced 16B-per-lane row stores
        __syncthreads();                      // main-loop LDS reads complete
#pragma unroll
        for (int nt = 0; nt < 4; ++nt) {
            const int n  = n0 + wn + nt * 16 + l16;
            const float bv = bias[n];
            const int dd = wn + nt * 16 + l16;
#pragma unroll
            for (int mt = 0; mt < 4; ++mt)
#pragma unroll
                for (int r = 0; r < 4; ++r) {
                    const int tl = wm + mt * 16 + quad * 4 + r;
                    smem[dd * 136 + tl] = (__bf16)(acc[mt][nt][r] + bv);
                }
        }
        __syncthreads();
#pragma unroll
        for (int i = 0; i < 8; ++i) {
            int s = i * 256 + tid;
            int dd = s >> 4, c = s & 15;
            bf16x8 vv = *(const bf16x8*)(smem + dd * 136 + c * 8);
            *(bf16x8*)(VT + ((size_t)bh * DK + dd) * T_ + t0 + c * 8) = vv;
        }
    } else {
        const float qscale = which ? 0.12751740f : 1.0f;  // log2e/sqrt(128)
        __bf16* dst = which ? Qh : Kh;
#pragma unroll
        for (int nt = 0; nt < 4; ++nt) {
            const int n  = n0 + wn + nt * 16 + l16;
            const float bv = bias[n];
            const int dd = wn + nt * 16 + l16;
            // rope freq (revolutions per t): 10000^(-(dd>>1)/64) / (2pi)
            const float freq_rev = 0.15915494309189535f *
                exp2f((float)(dd >> 1) * (-13.287712379549449f / 64.f));
#pragma unroll
            for (int mt = 0; mt < 4; ++mt)
#pragma unroll
                for (int r = 0; r < 4; ++r) {
                    const int t = t0 + wm + mt * 16 + quad * 4 + r;
                    const float val = acc[mt][nt][r] + bv;
                    const float other = __shfl_xor(val, 1);
                    const float x1 = (dd & 1) ? other : val;   // even-col value
                    const float x2 = (dd & 1) ? val : other;   // odd-col value
                    float rev = (float)t * freq_rev;
                    rev -= floorf(rev);
                    const float ang = rev * 6.283185307179586f;
                    const float sn = __sinf(ang), cn = __cosf(ang);
                    const float res = (dd & 1) ? (x1 * sn + x2 * cn)
                                               : (x1 * cn - x2 * sn);
                    dst[((size_t)bh * T_ + t) * DK + dd] = (__bf16)(res * qscale);
                }
        }
    }
}

// ---------------------------------------------------------------------------
// flash attention, swapped-operand (R4 verified): mfma(kf,qf) -> S^T, lane
// owns one q-row (scalar softmax state, 2 shfls), P^T via 8B-swizzled LDS,
// O^T = mfma(vf,pb). K/V double-buffered + counted vmcnt(8) + setprio.
// ---------------------------------------------------------------------------
__global__ __launch_bounds__(256)
void fa_kernel(const __bf16* __restrict__ Qg, const __bf16* __restrict__ Kg,
               const __bf16* __restrict__ VTg, __bf16* __restrict__ Og) {
    __shared__ __align__(16) __bf16 Ks[2][64 * 128];   // 32KB
    __shared__ __align__(16) __bf16 Vs[2][128 * 64];   // 32KB
    __shared__ __align__(16) __bf16 Ps[4][16 * 64];    //  8KB (per-wave 2KB)
    const int tid  = threadIdx.x;
    const int lane = tid & 63, wave = tid >> 6;
    const int quad = lane >> 4, l16 = lane & 15;
    const int bh = blockIdx.y;
    const int j  = blockIdx.x;          // 0..15
    const int b = bh >> 4, h = bh & 15;

    const __bf16* Kb = Kg  + (size_t)bh * T_ * DK;
    const __bf16* Vb = VTg + (size_t)bh * DK * T_;
    __bf16* Psw = Ps[wave];
    const int swzP = (l16 & 7) << 1;    // even XOR mask on 4-elem (8B) groups

    const floatx4 z4 = {0.f, 0.f, 0.f, 0.f};

    int           sK[4], sV[4];
    const __bf16* gK[4];
    const __bf16* gV[4];
#pragma unroll
    for (int i = 0; i < 4; ++i) {
        int s = i * 256 + tid;
        { int row = s >> 4, cs = s & 15; int gc = cs ^ (row & 7);
          sK[i] = s * 8; gK[i] = Kb + (size_t)row * DK + gc * 8; }
        { int row = s >> 3, cs = s & 7;  int gc = cs ^ (row & 7);
          sV[i] = s * 8; gV[i] = Vb + (size_t)row * T_ + gc * 8; }
    }

    for (int half = 0; half < 2; ++half) {
        const int qt = half ? (31 - j) : j;
        const int q0 = qt * 64;
        const int qpos = q0 + wave * 16 + l16;   // this lane's q-row

        // ---- prologue: stage Q tile through Ks[0], lift to registers ----
        __syncthreads();   // WAR: previous half's reads of Ks/Vs (full drain)
        {
            const __bf16* Qb = Qg + (size_t)(bh * T_ + q0) * DK;
#pragma unroll
            for (int i = 0; i < 4; ++i) {
                int s = i * 256 + tid;
                int row = s >> 4, cs = s & 15;
                int gc = cs ^ (row & 7);
                async_copy16(Qb + row * DK + gc * 8, &Ks[0][0] + s * 8);
            }
        }
        __syncthreads();   // vmcnt(0): Q staged
        bf16x8 qf[4];
#pragma unroll
        for (int ks = 0; ks < 4; ++ks) {
            int row = wave * 16 + l16;
            int c = (ks * 4 + quad) ^ (row & 7);
            qf[ks] = *(const bf16x8*)(&Ks[0][0] + row * DK + c * 8);
        }
        __syncthreads();   // lgkmcnt(0): qf in registers before Ks[0] overwrite

        // prologue prefetch: tile 0 -> buf 0
#pragma unroll
        for (int i = 0; i < 4; ++i) async_copy16(gK[i], &Ks[0][0] + sK[i]);
#pragma unroll
        for (int i = 0; i < 4; ++i) async_copy16(gV[i], &Vs[0][0] + sV[i]);

        float m_i = -1e30f, l_i = 0.f;
        floatx4 accO[8];   // O^T tiles: accO[dt] -> d = dt*16+quad*4+r, q = l16
#pragma unroll
        for (int dt = 0; dt < 8; ++dt) accO[dt] = z4;

        for (int kt = 0; kt <= qt; ++kt) {
            const int cur = kt & 1;
            if (kt < qt) {
                const int nb = cur ^ 1;
                const size_t koff = (size_t)(kt + 1) * 64 * DK;
                const size_t voff = (size_t)(kt + 1) * 64;
#pragma unroll
                for (int i = 0; i < 4; ++i) async_copy16(gK[i] + koff, &Ks[nb][0] + sK[i]);
#pragma unroll
                for (int i = 0; i < 4; ++i) async_copy16(gV[i] + voff, &Vs[nb][0] + sV[i]);
                asm volatile("s_waitcnt vmcnt(8)" ::: "memory");
            } else {
                asm volatile("s_waitcnt vmcnt(0)" ::: "memory");
            }
            __builtin_amdgcn_s_barrier();

            const __bf16* Kcur = &Ks[cur][0];
            const __bf16* Vcur = &Vs[cur][0];

            // S^T strip: sc[nt] covers k = kt*64+nt*16+quad*4+r, q = l16
            floatx4 sc[4];
#pragma unroll
            for (int nt = 0; nt < 4; ++nt) sc[nt] = z4;
            __builtin_amdgcn_s_setprio(1);
#pragma unroll
            for (int ks = 0; ks < 4; ++ks)
#pragma unroll
                for (int nt = 0; nt < 4; ++nt) {
                    int row = nt * 16 + l16;
                    int c = (ks * 4 + quad) ^ (row & 7);
                    bf16x8 kf = *(const bf16x8*)(Kcur + row * DK + c * 8);
                    sc[nt] = __builtin_amdgcn_mfma_f32_16x16x32_bf16(kf, qf[ks], sc[nt], 0, 0, 0);
                }
            __builtin_amdgcn_s_setprio(0);

            // causal mask + in-lane max over own 16 k-values
            float mnew = -1e30f;
            if (kt == qt) {
#pragma unroll
                for (int nt = 0; nt < 4; ++nt) {
                    int kbase = kt * 64 + nt * 16 + quad * 4;
#pragma unroll
                    for (int r = 0; r < 4; ++r) {
                        float v = sc[nt][r];
                        v = (kbase + r > qpos) ? -1e30f : v;
                        sc[nt][r] = v;
                        mnew = fmaxf(mnew, v);
                    }
                }
            } else {
#pragma unroll
                for (int nt = 0; nt < 4; ++nt)
#pragma unroll
                    for (int r = 0; r < 4; ++r) mnew = fmaxf(mnew, sc[nt][r]);
            }
            // cross-quad reduce (q-row spread over lanes l16, l16+16, +32, +48)
            mnew = fmaxf(mnew, __shfl_xor(mnew, 16));
            mnew = fmaxf(mnew, __shfl_xor(mnew, 32));
            const float mi = fmaxf(m_i, mnew);
            const float alpha = exp2f(m_i - mi);   // base-2 softmax
            m_i = mi;

            float rs = 0.f;
#pragma unroll
            for (int nt = 0; nt < 4; ++nt)
#pragma unroll
                for (int r = 0; r < 4; ++r) {
                    float pv = exp2f(sc[nt][r] - mi);
                    sc[nt][r] = pv;
                    rs += pv;
                }
            rs += __shfl_xor(rs, 16);
            rs += __shfl_xor(rs, 32);
            l_i = l_i * alpha + rs;
#pragma unroll
            for (int dt = 0; dt < 8; ++dt)
#pragma unroll
                for (int r = 0; r < 4; ++r) accO[dt][r] *= alpha;

            // P^T -> LDS: row q=l16 (64 k's), 8B groups swizzled by g^=swzP
#pragma unroll
            for (int nt = 0; nt < 4; ++nt) {
                bf16x4 pw;
                pw.x = (__bf16)sc[nt][0]; pw.y = (__bf16)sc[nt][1];
                pw.z = (__bf16)sc[nt][2]; pw.w = (__bf16)sc[nt][3];
                int g = (nt * 4 + quad) ^ swzP;
                *(bf16x4*)(Psw + l16 * 64 + g * 4) = pw;
            }
            // O^T += V^T . P^T  (A = Vs rows, B = P^T frags from Psw)
            __builtin_amdgcn_s_setprio(1);
#pragma unroll
            for (int kc = 0; kc < 2; ++kc) {
                int gk = (kc * 8 + quad * 2) ^ swzP;   // even -> 16B aligned
                bf16x8 pb = *(const bf16x8*)(Psw + l16 * 64 + gk * 4);
#pragma unroll
                for (int dt = 0; dt < 8; ++dt) {
                    int vrow = dt * 16 + l16;
                    int vch = (kc * 4 + quad) ^ (vrow & 7);
                    bf16x8 vf = *(const bf16x8*)(Vcur + vrow * 64 + vch * 8);
                    accO[dt] = __builtin_amdgcn_mfma_f32_16x16x32_bf16(vf, pb, accO[dt], 0, 0, 0);
                }
            }
            __builtin_amdgcn_s_setprio(0);

            __builtin_amdgcn_s_barrier();
        }

        // ---- epilogue: accO is O^T; lane writes 8x 8B runs of its q-row ----
        const float inv = 1.0f / l_i;
        __bf16* orow = Og + (size_t)(b * T_ + qpos) * D_ + h * DK;
#pragma unroll
        for (int dt = 0; dt < 8; ++dt) {
            bf16x4 ow;
            ow.x = (__bf16)(accO[dt][0] * inv);
            ow.y = (__bf16)(accO[dt][1] * inv);
            ow.z = (__bf16)(accO[dt][2] * inv);
            ow.w = (__bf16)(accO[dt][3] * inv);
            *(bf16x4*)(orow + dt * 16 + quad * 4) = ow;
        }
    }
}

// ---------------------------------------------------------------------------
extern "C" void kernel_launch(void* const* d_in, const int* in_sizes, int n_in,
                              void* d_out, int out_size, void* d_ws, size_t ws_size,
                              hipStream_t stream) {
    const float* x    = (const float*)d_in[0];
    const float* Wkqv = (const float*)d_in[1];
    const float* bkqv = (const float*)d_in[2];
    const float* Wo   = (const float*)d_in[3];
    const float* bo   = (const float*)d_in[4];
    float* out = (float*)d_out;

    // workspace layout (112 MiB used)
    char* p = (char*)d_ws;
    __bf16* xb    = (__bf16*)p; p += (size_t)BT_ * D_ * 2;  // 16 MiB
    __bf16* WkqvT = (__bf16*)p; p += (size_t)D_ * N3 * 2;   // 24 MiB
    __bf16* WoT   = (__bf16*)p; p += (size_t)D_ * D_ * 2;   //  8 MiB
    __bf16* qh    = (__bf16*)p; p += (size_t)BT_ * D_ * 2;  // 16 MiB
    __bf16* kh    = (__bf16*)p; p += (size_t)BT_ * D_ * 2;  // 16 MiB
    __bf16* vT    = (__bf16*)p; p += (size_t)BT_ * D_ * 2;  // 16 MiB
    __bf16* ao    = (__bf16*)p; p += (size_t)BT_ * D_ * 2;  // 16 MiB

    cast_bf16_kernel<<<(BT_ * D_ / 4 + 255) / 256, 256, 0, stream>>>(x, xb, BT_ * D_ / 4);
    transcast_kernel<<<dim3(N3 / 32, D_ / 32), dim3(32, 8), 0, stream>>>(Wkqv, WkqvT, D_, N3);
    transcast_kernel<<<dim3(D_ / 32, D_ / 32), dim3(32, 8), 0, stream>>>(Wo, WoT, D_, D_);
    gemm_kqv<<<dim3(N3 / 128, BT_ / 128), 256, 0, stream>>>(xb, WkqvT, bkqv, kh, qh, vT, BT_, N3, D_);
    fa_kernel<<<dim3(16, B_ * H_), 256, 0, stream>>>(qh, kh, vT, ao);
    gemm_bt<float><<<dim3(D_ / 128, BT_ / 128), 256, 0, stream>>>(ao, WoT, bo, out, BT_, D_, D_);
}